// Round 1
// baseline (2559.668 us; speedup 1.0000x reference)
//
#include <hip/hip_runtime.h>
#include <hip/hip_bf16.h>

typedef unsigned int u32;

#define T_STEPS 4
#define N_NODES 50000
#define E_EDGES 1600000
#define HID 128
#define OUT_CH 16

// ---- workspace layout (bytes) ----
#define OFF_H     0u            // h bf16 [N*128]            = 12,800,000
#define OFF_DEG   12800000u     // deg   [N] int             = 200,000
#define OFF_ZPAD  13000000u     // z_sum padded [128*32] f32 = 16,384  (contiguous w/ deg for one memset)
#define OFF_RS    13016384u     // row_start [N+1] int       = 200,004
#define OFF_CUR   13216640u     // cursor [N] int            = 200,000
#define OFF_CSR   13416704u     // csr src [E] int           = 6,400,000
#define OFF_HST   19816704u     // h_state [128] f32         = 512

__device__ __forceinline__ float bflo(u32 u) { return __uint_as_float(u << 16); }
__device__ __forceinline__ float bfhi(u32 u) { return __uint_as_float(u & 0xFFFF0000u); }

// h = bf16( x @ W^T + b ), x:[N,128] W:[128,128] row-major
// Each wave: 64 output channels (half = wave&1), W rows held in 128 VGPRs/lane,
// x row elements are wave-uniform -> scalar loads -> pure VALU FMA inner loop.
__global__ void gemm_kernel(const float* __restrict__ x,
                            const float* __restrict__ W,
                            const float* __restrict__ b,
                            __hip_bfloat16* __restrict__ h) {
    const int lane = threadIdx.x & 63;
    const int wv   = __builtin_amdgcn_readfirstlane((int)(threadIdx.x >> 6));
    const int c    = (wv & 1) * 64 + lane;   // output channel

    float wreg[128];
#pragma unroll
    for (int k = 0; k < 128; ++k) wreg[k] = W[c * 128 + k];
    const float bias = b[c];

    const int nPairs = N_NODES / 4;          // 12500, N divisible by 4
    const int pair0  = blockIdx.x * 2 + (wv >> 1);
    const int pstr   = gridDim.x * 2;
    for (int p = pair0; p < nPairs; p += pstr) {
        const int n0 = p * 4;
        const float* xr = x + (size_t)n0 * 128;
        float a0 = 0.f, a1 = 0.f, a2 = 0.f, a3 = 0.f;
#pragma unroll
        for (int k = 0; k < 128; ++k) {
            const float wk = wreg[k];
            a0 = fmaf(xr[k],       wk, a0);
            a1 = fmaf(xr[128 + k], wk, a1);
            a2 = fmaf(xr[256 + k], wk, a2);
            a3 = fmaf(xr[384 + k], wk, a3);
        }
        h[(n0 + 0) * 128 + c] = __float2bfloat16(a0 + bias);
        h[(n0 + 1) * 128 + c] = __float2bfloat16(a1 + bias);
        h[(n0 + 2) * 128 + c] = __float2bfloat16(a2 + bias);
        h[(n0 + 3) * 128 + c] = __float2bfloat16(a3 + bias);
    }
}

__global__ void count_kernel(const int* __restrict__ dst, int* __restrict__ deg) {
    int i = blockIdx.x * blockDim.x + threadIdx.x;
    const int str = gridDim.x * blockDim.x;
    for (; i < E_EDGES; i += str) atomicAdd(&deg[dst[i]], 1);
}

// single-block exclusive scan of deg -> row_start, cursor; row_start[N]=E
__global__ void scan_kernel(const int* __restrict__ deg,
                            int* __restrict__ row_start,
                            int* __restrict__ cursor) {
    __shared__ int part[1024];
    const int tid = threadIdx.x;
    const int chunk = (N_NODES + 1023) / 1024;   // 49
    const int begin = tid * chunk;
    const int end   = min(begin + chunk, N_NODES);
    int s = 0;
    for (int i = begin; i < end; ++i) s += deg[i];
    part[tid] = s;
    __syncthreads();
    for (int d = 1; d < 1024; d <<= 1) {
        int v = (tid >= d) ? part[tid - d] : 0;
        __syncthreads();
        part[tid] += v;
        __syncthreads();
    }
    int run = (tid == 0) ? 0 : part[tid - 1];
    for (int i = begin; i < end; ++i) {
        row_start[i] = run;
        cursor[i]    = run;
        run += deg[i];
    }
    if (tid == 1023) row_start[N_NODES] = part[1023];
}

__global__ void fill_kernel(const int* __restrict__ src, const int* __restrict__ dst,
                            int* __restrict__ cursor, int* __restrict__ csr) {
    int i = blockIdx.x * blockDim.x + threadIdx.x;
    const int str = gridDim.x * blockDim.x;
    for (; i < E_EDGES; i += str) {
        const int d = dst[i];
        const int pos = atomicAdd(&cursor[d], 1);
        csr[pos] = src[i];
    }
}

// One wave per dst node. Lane holds channels (2*lane, 2*lane+1) as one dword of bf16x2.
// src indices are wave-uniform (scalar loads); each src row read = coalesced 256B.
// Per-node: acc = h[n] (self loop) + sum h[src]; z += relu(acc/(cnt+1)).
__global__ __launch_bounds__(256) void gather_kernel(const u32* __restrict__ h2,
                                                     const int* __restrict__ row_start,
                                                     const int* __restrict__ csr,
                                                     float* __restrict__ z_pad) {
    const int lane = threadIdx.x & 63;
    const int wv   = __builtin_amdgcn_readfirstlane((int)(threadIdx.x >> 6));
    const int gw   = blockIdx.x * 4 + wv;
    const int nw   = gridDim.x * 4;

    float zx = 0.f, zy = 0.f;
    for (int n = gw; n < N_NODES; n += nw) {
        const int rs  = row_start[n];
        const int cnt = row_start[n + 1] - rs;
        const u32 us = h2[n * 64 + lane];          // self loop
        float ax = bflo(us), ay = bfhi(us);
        const int* lst = csr + rs;
        int i = 0;
        for (; i + 4 <= cnt; i += 4) {
            const int s0 = lst[i], s1 = lst[i + 1], s2 = lst[i + 2], s3 = lst[i + 3];
            const u32 u0 = h2[s0 * 64 + lane];
            const u32 u1 = h2[s1 * 64 + lane];
            const u32 u2 = h2[s2 * 64 + lane];
            const u32 u3 = h2[s3 * 64 + lane];
            ax += bflo(u0) + bflo(u1) + bflo(u2) + bflo(u3);
            ay += bfhi(u0) + bfhi(u1) + bfhi(u2) + bfhi(u3);
        }
        for (; i < cnt; ++i) {
            const u32 u0 = h2[lst[i] * 64 + lane];
            ax += bflo(u0);
            ay += bfhi(u0);
        }
        const float inv = 1.0f / (float)(cnt + 1);
        zx += fmaxf(ax * inv, 0.f);
        zy += fmaxf(ay * inv, 0.f);
    }

    __shared__ float red[4][64][2];
    red[wv][lane][0] = zx;
    red[wv][lane][1] = zy;
    __syncthreads();
    if (threadIdx.x < 64) {
        const float sx = red[0][lane][0] + red[1][lane][0] + red[2][lane][0] + red[3][lane][0];
        const float sy = red[0][lane][1] + red[1][lane][1] + red[2][lane][1] + red[3][lane][1];
        atomicAdd(&z_pad[(2 * lane) * 32], sx);       // 128B-strided slots: no same-line atomic pileup
        atomicAdd(&z_pad[(2 * lane + 1) * 32], sy);
    }
}

__global__ __launch_bounds__(512) void gru_kernel(const float* __restrict__ z_pad,
                                                  const float* __restrict__ W_ih,
                                                  const float* __restrict__ W_hh,
                                                  const float* __restrict__ b_ih,
                                                  const float* __restrict__ b_hh,
                                                  float* __restrict__ h_state,
                                                  const float* __restrict__ W_cls,
                                                  const float* __restrict__ b_cls,
                                                  float* __restrict__ out,
                                                  int do_cls) {
    __shared__ float zm[128], hs[128], gi[384], gh[384], hn[128];
    const int tid = threadIdx.x;
    if (tid < 128) {
        zm[tid] = z_pad[tid * 32] * (1.0f / (float)N_NODES);
        hs[tid] = h_state[tid];
    }
    __syncthreads();
    if (tid < 384) {
        float a = b_ih[tid], g = b_hh[tid];
        const float* wi = W_ih + tid * 128;
        const float* wh = W_hh + tid * 128;
#pragma unroll 8
        for (int k = 0; k < 128; ++k) {
            a = fmaf(zm[k], wi[k], a);
            g = fmaf(hs[k], wh[k], g);
        }
        gi[tid] = a;
        gh[tid] = g;
    }
    __syncthreads();
    if (tid < 128) {
        const float r  = 1.f / (1.f + expf(-(gi[tid] + gh[tid])));
        const float zg = 1.f / (1.f + expf(-(gi[128 + tid] + gh[128 + tid])));
        const float ng = tanhf(gi[256 + tid] + r * gh[256 + tid]);
        const float hv = (1.f - zg) * ng + zg * hs[tid];
        h_state[tid] = hv;
        hn[tid] = hv;
    }
    __syncthreads();
    if (do_cls && tid < OUT_CH) {
        float a = b_cls[tid];
        const float* wc = W_cls + tid * 128;
#pragma unroll 8
        for (int k = 0; k < 128; ++k) a = fmaf(hn[k], wc[k], a);
        out[tid] = a;
    }
}

extern "C" void kernel_launch(void* const* d_in, const int* in_sizes, int n_in,
                              void* d_out, int out_size, void* d_ws, size_t ws_size,
                              hipStream_t stream) {
    const float* xs    = (const float*)d_in[0];
    const int*   edges = (const int*)d_in[1];
    const float* W_gcn = (const float*)d_in[2];
    const float* b_gcn = (const float*)d_in[3];
    const float* W_ih  = (const float*)d_in[4];
    const float* W_hh  = (const float*)d_in[5];
    const float* b_ih  = (const float*)d_in[6];
    const float* b_hh  = (const float*)d_in[7];
    const float* W_cls = (const float*)d_in[8];
    const float* b_cls = (const float*)d_in[9];
    float* out = (float*)d_out;

    char* ws = (char*)d_ws;
    __hip_bfloat16* h = (__hip_bfloat16*)(ws + OFF_H);
    int*   deg       = (int*)(ws + OFF_DEG);
    float* z_pad     = (float*)(ws + OFF_ZPAD);
    int*   row_start = (int*)(ws + OFF_RS);
    int*   cursor    = (int*)(ws + OFF_CUR);
    int*   csr       = (int*)(ws + OFF_CSR);
    float* h_state   = (float*)(ws + OFF_HST);

    hipMemsetAsync(h_state, 0, 128 * sizeof(float), stream);

    for (int t = 0; t < T_STEPS; ++t) {
        const float* x_t  = xs + (size_t)t * N_NODES * 128;
        const int* src_t  = edges + (size_t)t * 2 * E_EDGES;
        const int* dst_t  = src_t + E_EDGES;

        // zero deg + z_pad (contiguous region)
        hipMemsetAsync(deg, 0, 200000 + 16384, stream);

        gemm_kernel<<<1024, 256, 0, stream>>>(x_t, W_gcn, b_gcn, h);
        count_kernel<<<2048, 256, 0, stream>>>(dst_t, deg);
        scan_kernel<<<1, 1024, 0, stream>>>(deg, row_start, cursor);
        fill_kernel<<<2048, 256, 0, stream>>>(src_t, dst_t, cursor, csr);
        gather_kernel<<<1024, 256, 0, stream>>>((const u32*)h, row_start, csr, z_pad);
        gru_kernel<<<1, 512, 0, stream>>>(z_pad, W_ih, W_hh, b_ih, b_hh, h_state,
                                          W_cls, b_cls, out, (t == T_STEPS - 1) ? 1 : 0);
    }
}

// Round 2
// 2180.928 us; speedup vs baseline: 1.1737x; 1.1737x over previous
//
#include <hip/hip_runtime.h>
#include <hip/hip_bf16.h>

typedef unsigned int u32;

#define T_STEPS 4
#define N_NODES 50000
#define E_EDGES 1600000
#define HID 128
#define OUT_CH 16

// ---- workspace layout (bytes) ----
#define OFF_H     0u            // h bf16 [N*128]            = 12,800,000
#define OFF_DEG   12800000u     // deg   [N] int             = 200,000
#define OFF_ZPAD  13000000u     // z_sum padded [128*32] f32 = 16,384  (contiguous w/ deg for one memset)
#define OFF_RS    13016384u     // row_start [N+1] int       = 200,004
#define OFF_CUR   13216640u     // cursor [N] int            = 200,000
#define OFF_CSR   13416704u     // csr src [E] int           = 6,400,000
#define OFF_HST   19816704u     // h_state [128] f32         = 512
#define OFF_WT    19817216u     // W_gcn transposed [128*128] f32 = 65,536

__device__ __forceinline__ float bflo(u32 u) { return __uint_as_float(u << 16); }
__device__ __forceinline__ float bfhi(u32 u) { return __uint_as_float(u & 0xFFFF0000u); }

// Wt[k*128 + c] = W[c*128 + k]; run once per launch (W constant across steps)
__global__ void transpose_kernel(const float* __restrict__ W, float* __restrict__ Wt) {
    const int i = blockIdx.x * 256 + threadIdx.x;   // 16384 total
    const int c = i >> 7, k = i & 127;
    Wt[k * 128 + c] = W[c * 128 + k];
}

// h = bf16( x @ W^T + b ), x:[N,128], Wt:[k][c] (transposed for coalesced reload)
// Wave = 64 output channels (half = wv&1) x 16 nodes. k tiled by 32:
// wreg[32] coalesced from Wt (L1-hit), x elements wave-uniform (broadcast/scalar).
// Peak live regs ~ 32 wreg + 16 acc + addressing: no spill (R0 lesson: wreg[128] spilled).
__global__ __launch_bounds__(256) void gemm_kernel(const float* __restrict__ x,
                                                   const float* __restrict__ Wt,
                                                   const float* __restrict__ b,
                                                   __hip_bfloat16* __restrict__ h) {
    const int lane = threadIdx.x & 63;
    const int wv   = __builtin_amdgcn_readfirstlane((int)(threadIdx.x >> 6));
    const int c    = (wv & 1) * 64 + lane;   // output channel
    const float bias = b[c];

    const int nGroups = N_NODES / 16;        // 3125
    int g = blockIdx.x * 2 + (wv >> 1);
    const int gstr = gridDim.x * 2;
    for (; g < nGroups; g += gstr) {
        const int n0 = g * 16;
        const float* xr = x + (size_t)n0 * 128;
        float acc[16];
#pragma unroll
        for (int i = 0; i < 16; ++i) acc[i] = 0.f;

        for (int kc = 0; kc < 128; kc += 32) {
            float wreg[32];
#pragma unroll
            for (int j = 0; j < 32; ++j) wreg[j] = Wt[(kc + j) * 128 + c];
#pragma unroll
            for (int n = 0; n < 16; ++n) {
                const float* xn = xr + n * 128 + kc;
#pragma unroll
                for (int j = 0; j < 32; ++j) acc[n] = fmaf(xn[j], wreg[j], acc[n]);
            }
        }
#pragma unroll
        for (int n = 0; n < 16; ++n)
            h[(size_t)(n0 + n) * 128 + c] = __float2bfloat16(acc[n] + bias);
    }
}

__global__ void count_kernel(const int* __restrict__ dst, int* __restrict__ deg) {
    int i = blockIdx.x * blockDim.x + threadIdx.x;
    const int str = gridDim.x * blockDim.x;
    for (; i < E_EDGES; i += str) atomicAdd(&deg[dst[i]], 1);
}

// single-block exclusive scan of deg -> row_start, cursor; row_start[N]=E
__global__ void scan_kernel(const int* __restrict__ deg,
                            int* __restrict__ row_start,
                            int* __restrict__ cursor) {
    __shared__ int part[1024];
    const int tid = threadIdx.x;
    const int chunk = (N_NODES + 1023) / 1024;   // 49
    const int begin = tid * chunk;
    const int end   = min(begin + chunk, N_NODES);
    int s = 0;
    for (int i = begin; i < end; ++i) s += deg[i];
    part[tid] = s;
    __syncthreads();
    for (int d = 1; d < 1024; d <<= 1) {
        int v = (tid >= d) ? part[tid - d] : 0;
        __syncthreads();
        part[tid] += v;
        __syncthreads();
    }
    int run = (tid == 0) ? 0 : part[tid - 1];
    for (int i = begin; i < end; ++i) {
        row_start[i] = run;
        cursor[i]    = run;
        run += deg[i];
    }
    if (tid == 1023) row_start[N_NODES] = part[1023];
}

__global__ void fill_kernel(const int* __restrict__ src, const int* __restrict__ dst,
                            int* __restrict__ cursor, int* __restrict__ csr) {
    int i = blockIdx.x * blockDim.x + threadIdx.x;
    const int str = gridDim.x * blockDim.x;
    for (; i < E_EDGES; i += str) {
        const int d = dst[i];
        const int pos = atomicAdd(&cursor[d], 1);
        csr[pos] = src[i];
    }
}

// One wave per dst node. Lane holds channels (2*lane, 2*lane+1) as one dword of bf16x2.
// src indices are wave-uniform (scalar loads); each src row read = coalesced 256B.
// Per-node: acc = h[n] (self loop) + sum h[src]; z += relu(acc/(cnt+1)).
__global__ __launch_bounds__(256) void gather_kernel(const u32* __restrict__ h2,
                                                     const int* __restrict__ row_start,
                                                     const int* __restrict__ csr,
                                                     float* __restrict__ z_pad) {
    const int lane = threadIdx.x & 63;
    const int wv   = __builtin_amdgcn_readfirstlane((int)(threadIdx.x >> 6));
    const int gw   = blockIdx.x * 4 + wv;
    const int nw   = gridDim.x * 4;

    float zx = 0.f, zy = 0.f;
    for (int n = gw; n < N_NODES; n += nw) {
        const int rs  = row_start[n];
        const int cnt = row_start[n + 1] - rs;
        const u32 us = h2[n * 64 + lane];          // self loop
        float ax = bflo(us), ay = bfhi(us);
        const int* lst = csr + rs;
        int i = 0;
        for (; i + 4 <= cnt; i += 4) {
            const int s0 = lst[i], s1 = lst[i + 1], s2 = lst[i + 2], s3 = lst[i + 3];
            const u32 u0 = h2[s0 * 64 + lane];
            const u32 u1 = h2[s1 * 64 + lane];
            const u32 u2 = h2[s2 * 64 + lane];
            const u32 u3 = h2[s3 * 64 + lane];
            ax += bflo(u0) + bflo(u1) + bflo(u2) + bflo(u3);
            ay += bfhi(u0) + bfhi(u1) + bfhi(u2) + bfhi(u3);
        }
        for (; i < cnt; ++i) {
            const u32 u0 = h2[lst[i] * 64 + lane];
            ax += bflo(u0);
            ay += bfhi(u0);
        }
        const float inv = 1.0f / (float)(cnt + 1);
        zx += fmaxf(ax * inv, 0.f);
        zy += fmaxf(ay * inv, 0.f);
    }

    __shared__ float red[4][64][2];
    red[wv][lane][0] = zx;
    red[wv][lane][1] = zy;
    __syncthreads();
    if (threadIdx.x < 64) {
        const float sx = red[0][lane][0] + red[1][lane][0] + red[2][lane][0] + red[3][lane][0];
        const float sy = red[0][lane][1] + red[1][lane][1] + red[2][lane][1] + red[3][lane][1];
        atomicAdd(&z_pad[(2 * lane) * 32], sx);       // 128B-strided slots: no same-line atomic pileup
        atomicAdd(&z_pad[(2 * lane + 1) * 32], sy);
    }
}

__global__ __launch_bounds__(512) void gru_kernel(const float* __restrict__ z_pad,
                                                  const float* __restrict__ W_ih,
                                                  const float* __restrict__ W_hh,
                                                  const float* __restrict__ b_ih,
                                                  const float* __restrict__ b_hh,
                                                  float* __restrict__ h_state,
                                                  const float* __restrict__ W_cls,
                                                  const float* __restrict__ b_cls,
                                                  float* __restrict__ out,
                                                  int do_cls) {
    __shared__ float zm[128], hs[128], gi[384], gh[384], hn[128];
    const int tid = threadIdx.x;
    if (tid < 128) {
        zm[tid] = z_pad[tid * 32] * (1.0f / (float)N_NODES);
        hs[tid] = h_state[tid];
    }
    __syncthreads();
    if (tid < 384) {
        float a = b_ih[tid], g = b_hh[tid];
        const float* wi = W_ih + tid * 128;
        const float* wh = W_hh + tid * 128;
#pragma unroll 8
        for (int k = 0; k < 128; ++k) {
            a = fmaf(zm[k], wi[k], a);
            g = fmaf(hs[k], wh[k], g);
        }
        gi[tid] = a;
        gh[tid] = g;
    }
    __syncthreads();
    if (tid < 128) {
        const float r  = 1.f / (1.f + expf(-(gi[tid] + gh[tid])));
        const float zg = 1.f / (1.f + expf(-(gi[128 + tid] + gh[128 + tid])));
        const float ng = tanhf(gi[256 + tid] + r * gh[256 + tid]);
        const float hv = (1.f - zg) * ng + zg * hs[tid];
        h_state[tid] = hv;
        hn[tid] = hv;
    }
    __syncthreads();
    if (do_cls && tid < OUT_CH) {
        float a = b_cls[tid];
        const float* wc = W_cls + tid * 128;
#pragma unroll 8
        for (int k = 0; k < 128; ++k) a = fmaf(hn[k], wc[k], a);
        out[tid] = a;
    }
}

extern "C" void kernel_launch(void* const* d_in, const int* in_sizes, int n_in,
                              void* d_out, int out_size, void* d_ws, size_t ws_size,
                              hipStream_t stream) {
    const float* xs    = (const float*)d_in[0];
    const int*   edges = (const int*)d_in[1];
    const float* W_gcn = (const float*)d_in[2];
    const float* b_gcn = (const float*)d_in[3];
    const float* W_ih  = (const float*)d_in[4];
    const float* W_hh  = (const float*)d_in[5];
    const float* b_ih  = (const float*)d_in[6];
    const float* b_hh  = (const float*)d_in[7];
    const float* W_cls = (const float*)d_in[8];
    const float* b_cls = (const float*)d_in[9];
    float* out = (float*)d_out;

    char* ws = (char*)d_ws;
    __hip_bfloat16* h = (__hip_bfloat16*)(ws + OFF_H);
    int*   deg       = (int*)(ws + OFF_DEG);
    float* z_pad     = (float*)(ws + OFF_ZPAD);
    int*   row_start = (int*)(ws + OFF_RS);
    int*   cursor    = (int*)(ws + OFF_CUR);
    int*   csr       = (int*)(ws + OFF_CSR);
    float* h_state   = (float*)(ws + OFF_HST);
    float* Wt        = (float*)(ws + OFF_WT);

    hipMemsetAsync(h_state, 0, 128 * sizeof(float), stream);
    transpose_kernel<<<64, 256, 0, stream>>>(W_gcn, Wt);

    for (int t = 0; t < T_STEPS; ++t) {
        const float* x_t  = xs + (size_t)t * N_NODES * 128;
        const int* src_t  = edges + (size_t)t * 2 * E_EDGES;
        const int* dst_t  = src_t + E_EDGES;

        // zero deg + z_pad (contiguous region)
        hipMemsetAsync(deg, 0, 200000 + 16384, stream);

        gemm_kernel<<<782, 256, 0, stream>>>(x_t, Wt, b_gcn, h);
        count_kernel<<<2048, 256, 0, stream>>>(dst_t, deg);
        scan_kernel<<<1, 1024, 0, stream>>>(deg, row_start, cursor);
        fill_kernel<<<2048, 256, 0, stream>>>(src_t, dst_t, cursor, csr);
        gather_kernel<<<1024, 256, 0, stream>>>((const u32*)h, row_start, csr, z_pad);
        gru_kernel<<<1, 512, 0, stream>>>(z_pad, W_ih, W_hh, b_ih, b_hh, h_state,
                                          W_cls, b_cls, out, (t == T_STEPS - 1) ? 1 : 0);
    }
}